// Round 7
// baseline (425.917 us; speedup 1.0000x reference)
//
#include <hip/hip_runtime.h>

// N=1048576 nodes, D=256 feats, G=2048 graphs, batch sorted (int32 on device).
// Out = [graph_embedding (G*256 f32), attention_scores (N f32)].
//
// R3's best streaming shape (8192 blocks, 4 waves x ~32-row contiguous slices,
// 4-deep float4 ring, cached loads) + two auxiliary-traffic cuts:
//   * partial kernel block-combines the 4 wave partials in LDS -> ONE packed
//     (max f32, argmax|tie<<30) record per block  (150MB RT -> 34MB RT)
//   * final kernel marks matches in a 4KB LDS bitmap, popcounts, and writes
//     scores in a single coalesced pass (no zero/readback/scale triple pass)

typedef float f32x4 __attribute__((ext_vector_type(4)));

constexpr int DIM = 256;
constexpr int SLICES = 16;     // wave-slices per graph (4 blocks x 4 waves)
constexpr int PB = 4;          // partial records per graph (one per block)
constexpr int MAXB = 32768;    // LDS bitmap capacity in bits (len fallback above)
constexpr float NEG_CLAMP = -3.4e38f;

__device__ __forceinline__ int lower_bound_i32(const int* __restrict__ a, int n, int v) {
    int lo = 0, hi = n;
    while (lo < hi) {
        int mid = (lo + hi) >> 1;
        if (a[mid] < v) lo = mid + 1; else hi = mid;
    }
    return lo;
}

__global__ void bounds_kernel(const int* __restrict__ batch, int* __restrict__ bounds,
                              int N, int G) {
    int g = blockIdx.x * blockDim.x + threadIdx.x;
    if (g < G)  bounds[g] = lower_bound_i32(batch, N, g);
    if (g == G) bounds[G] = N;
}

__global__ __launch_bounds__(256, 8)
void partial_kernel(const float* __restrict__ x,
                    const int* __restrict__ bounds,
                    float* __restrict__ pmax,          // [G][PB][DIM]
                    int* __restrict__ pam)             // [G][PB][DIM] am|tie<<30, or -1
{
    const int bid = blockIdx.x;          // g*PB + s
    const int g = bid >> 2;
    const int s = bid & 3;
    const int t = threadIdx.x;
    const int w = t >> 6;
    const int l = t & 63;
    const int wi = s * 4 + w;            // wave-slice 0..15

    const int start = bounds[g];
    const int end   = bounds[g + 1];
    const int len   = end - start;
    const int q     = (len + SLICES - 1) / SLICES;

    int a = start + wi * q;
    int b = a + q;
    if (a > end) a = end;
    if (b > end) b = end;
    const int n = b - a;

    const float NI = -__builtin_huge_valf();
    float m0 = NI, m1 = NI, m2 = NI, m3 = NI;
    int   a0 = -1, a1 = -1, a2 = -1, a3 = -1;
    unsigned int tieb = 0;

    // row r (relative to a), lane l -> p[r*64]
    const f32x4* __restrict__ p = (const f32x4*)x + (size_t)a * 64 + l;

#define UPD4(v, idx) do {                                             \
        bool g0 = (v).x > m0, g1 = (v).y > m1,                        \
             g2 = (v).z > m2, g3 = (v).w > m3;                        \
        tieb |= ((v).x == m0) ? 1u : 0u;                              \
        tieb |= ((v).y == m1) ? 2u : 0u;                              \
        tieb |= ((v).z == m2) ? 4u : 0u;                              \
        tieb |= ((v).w == m3) ? 8u : 0u;                              \
        a0 = g0 ? (idx) : a0;  m0 = g0 ? (v).x : m0;                  \
        a1 = g1 ? (idx) : a1;  m1 = g1 ? (v).y : m1;                  \
        a2 = g2 ? (idx) : a2;  m2 = g2 ? (v).z : m2;                  \
        a3 = g3 ? (idx) : a3;  m3 = g3 ? (v).w : m3;                  \
    } while (0)

    // 4-deep prefetch ring, statically indexed
    f32x4 f0 = (f32x4)(NI), f1 = f0, f2 = f0, f3 = f0;
    if (n > 0) f0 = p[0 * 64];
    if (n > 1) f1 = p[1 * 64];
    if (n > 2) f2 = p[2 * 64];
    if (n > 3) f3 = p[3 * 64];

    int k = 0;
    for (; k + 8 <= n; k += 4) {
        UPD4(f0, a + k + 0);  f0 = p[(size_t)(k + 4) * 64];
        UPD4(f1, a + k + 1);  f1 = p[(size_t)(k + 5) * 64];
        UPD4(f2, a + k + 2);  f2 = p[(size_t)(k + 6) * 64];
        UPD4(f3, a + k + 3);  f3 = p[(size_t)(k + 7) * 64];
    }
    const int rem = n - k;   // 0..7
    if (rem > 0) UPD4(f0, a + k + 0);
    if (rem > 1) UPD4(f1, a + k + 1);
    if (rem > 2) UPD4(f2, a + k + 2);
    if (rem > 3) UPD4(f3, a + k + 3);
    for (int r = k + 4; r < n; ++r) {
        f32x4 v = p[(size_t)r * 64];
        UPD4(v, a + r);
    }
#undef UPD4

    // per-wave packed records -> LDS (am in bits 0..29, tie in bit 30; empty -> -1)
    const int pk0 = (a0 >= 0) ? (a0 | (int)((tieb >> 0) & 1u) << 30) : -1;
    const int pk1 = (a1 >= 0) ? (a1 | (int)((tieb >> 1) & 1u) << 30) : -1;
    const int pk2 = (a2 >= 0) ? (a2 | (int)((tieb >> 2) & 1u) << 30) : -1;
    const int pk3 = (a3 >= 0) ? (a3 | (int)((tieb >> 3) & 1u) << 30) : -1;

    __shared__ float sm[4][DIM];
    __shared__ int   sk[4][DIM];
    const int c = l * 4;
    sm[w][c + 0] = m0;  sk[w][c + 0] = pk0;
    sm[w][c + 1] = m1;  sk[w][c + 1] = pk1;
    sm[w][c + 2] = m2;  sk[w][c + 2] = pk2;
    sm[w][c + 3] = m3;  sk[w][c + 3] = pk3;
    __syncthreads();

    // combine 4 waves for column t -> one block record
    const float M = fmaxf(fmaxf(sm[0][t], sm[1][t]), fmaxf(sm[2][t], sm[3][t]));
    int kout = -1;
    unsigned int tie = 0;
    #pragma unroll
    for (int ww = 0; ww < 4; ++ww) {
        const float mv = sm[ww][t];
        const int   kv = sk[ww][t];
        if (mv == M && kv != -1) {
            tie |= ((unsigned)kv >> 30) & 1u;      // within-slice duplicate of max
            if (kout == -1) kout = kv & 0x3FFFFFFF;
            else tie = 1u;                          // two slices attain M -> rescan
        }
    }
    const size_t base = ((size_t)g * PB + s) * DIM + t;
    pmax[base] = M;
    pam[base]  = (kout == -1) ? -1 : (kout | (int)(tie << 30));
}

__global__ __launch_bounds__(256, 8)
void final_kernel(const float* __restrict__ x,
                  const int* __restrict__ bounds,
                  const float* __restrict__ pmax,
                  const int* __restrict__ pam,
                  float* __restrict__ emb,
                  float* __restrict__ scores)
{
    const int g = blockIdx.x;
    const int t = threadIdx.x;
    const int start = bounds[g];
    const int end   = bounds[g + 1];
    const int len   = end - start;

    const size_t pb = (size_t)g * PB * DIM + t;
    const float pv0 = pmax[pb + 0 * DIM], pv1 = pmax[pb + 1 * DIM];
    const float pv2 = pmax[pb + 2 * DIM], pv3 = pmax[pb + 3 * DIM];
    const int   k0  = pam[pb + 0 * DIM],  k1  = pam[pb + 1 * DIM];
    const int   k2  = pam[pb + 2 * DIM],  k3  = pam[pb + 3 * DIM];

    const float M = fmaxf(fmaxf(pv0, pv1), fmaxf(pv2, pv3));
    emb[(size_t)g * DIM + t] = fmaxf(M, NEG_CLAMP);

    __shared__ unsigned int bm[MAXB / 32];   // 4 KB bitmap
    __shared__ float sred[4];

    if (len <= MAXB) {
        const int nw = (len + 31) >> 5;
        for (int i = t; i < nw; i += DIM) bm[i] = 0u;
        __syncthreads();

        bool rescan = false;
#define MARK(pvv, kk) do { if ((pvv) == M && (kk) != -1) {                        \
            const int rel = ((kk) & 0x3FFFFFFF) - start;                          \
            atomicOr(&bm[rel >> 5], 1u << (rel & 31));                            \
            rescan = rescan || ((((unsigned)(kk)) >> 30) & 1u); } } while (0)
        MARK(pv0, k0); MARK(pv1, k1); MARK(pv2, k2); MARK(pv3, k3);
#undef MARK
        if (rescan) {
            // rare exact-duplicate path: re-scan column t, mark all hits of M
            const float* __restrict__ col = x + t;
            for (int j = start; j < end; ++j)
                if (col[(size_t)j * DIM] == M) {
                    const int rel = j - start;
                    atomicOr(&bm[rel >> 5], 1u << (rel & 31));
                }
        }
        __syncthreads();

        float cnt = 0.0f;
        for (int i = t; i < nw; i += DIM) cnt += (float)__popc(bm[i]);
        for (int off = 32; off > 0; off >>= 1) cnt += __shfl_down(cnt, off, 64);
        if ((t & 63) == 0) sred[t >> 6] = cnt;
        __syncthreads();
        const float total = sred[0] + sred[1] + sred[2] + sred[3];
        const float inv = 1.0f / fmaxf(total, 1.0f);  // exact: numerator is 0 or 1

        // single coalesced pass over this graph's scores
        for (int j = start + t; j < end; j += DIM) {
            const int rel = j - start;
            scores[j] = ((bm[rel >> 5] >> (rel & 31)) & 1u) ? inv : 0.0f;
        }
    } else {
        // fallback for oversized segments (never hit at len~512): global path
        for (int j = start + t; j < end; j += DIM) scores[j] = 0.0f;
        __syncthreads();
        bool rescan = false;
#define MARKG(pvv, kk) do { if ((pvv) == M && (kk) != -1) {                       \
            scores[(kk) & 0x3FFFFFFF] = 1.0f;                                     \
            rescan = rescan || ((((unsigned)(kk)) >> 30) & 1u); } } while (0)
        MARKG(pv0, k0); MARKG(pv1, k1); MARKG(pv2, k2); MARKG(pv3, k3);
#undef MARKG
        if (rescan) {
            const float* __restrict__ col = x + t;
            for (int j = start; j < end; ++j)
                if (col[(size_t)j * DIM] == M) scores[j] = 1.0f;
        }
        __syncthreads();
        float cnt = 0.0f;
        for (int j = start + t; j < end; j += DIM) cnt += scores[j];
        for (int off = 32; off > 0; off >>= 1) cnt += __shfl_down(cnt, off, 64);
        if ((t & 63) == 0) sred[t >> 6] = cnt;
        __syncthreads();
        const float total = sred[0] + sred[1] + sred[2] + sred[3];
        const float inv = 1.0f / fmaxf(total, 1.0f);
        for (int j = start + t; j < end; j += DIM) scores[j] *= inv;
    }
}

extern "C" void kernel_launch(void* const* d_in, const int* in_sizes, int n_in,
                              void* d_out, int out_size, void* d_ws, size_t ws_size,
                              hipStream_t stream) {
    const float* x     = (const float*)d_in[0];
    const int*   batch = (const int*)d_in[1];

    const int N  = in_sizes[1];          // 1048576
    const int Dd = in_sizes[0] / N;      // 256
    const int G  = (out_size - N) / Dd;  // 2048

    float* emb    = (float*)d_out;
    float* scores = (float*)d_out + (size_t)G * Dd;

    // workspace layout (~17 MB; ws is ~4 GB)
    char* ws = (char*)d_ws;
    int* bounds = (int*)ws;
    size_t off = (((size_t)(G + 1) * sizeof(int)) + 1023) & ~(size_t)1023;
    float* pmax = (float*)(ws + off);  off += (size_t)G * PB * DIM * sizeof(float);
    int*   pam  = (int*)(ws + off);

    bounds_kernel<<<(G + 256) / 256, 256, 0, stream>>>(batch, bounds, N, G);
    partial_kernel<<<G * PB, 256, 0, stream>>>(x, bounds, pmax, pam);
    final_kernel<<<G, 256, 0, stream>>>(x, bounds, pmax, pam, emb, scores);
}

// Round 8
// 237.556 us; speedup vs baseline: 1.7929x; 1.7929x over previous
//
#include <hip/hip_runtime.h>

// N=1048576 nodes, D=256 feats, G=2048 graphs, batch sorted (int32 on device).
// Out = [graph_embedding (G*256 f32), attention_scores (N f32)].
//
// EXACT R3 structure (best known: 269us) with ONE change: nontemporal loads
// for the use-once x stream.
//  1) bounds_kernel : bounds[g] = lower_bound(batch, g), bounds[G] = N
//  2) partial_kernel: 4 blocks/graph x 4 waves = 16 wave-slices/graph
//     (~32 contiguous rows each), 4-deep float4 prefetch ring, NT loads.
//  3) final_kernel  : per graph, combine 16 partials/column, write emb,
//     mark matches in scores, (rare) tie rescan, count, scale.

typedef float f32x4 __attribute__((ext_vector_type(4)));

constexpr int DIM = 256;
constexpr int WSL = 16;                 // wave-slices per graph
constexpr float NEG_CLAMP = -3.4e38f;

__device__ __forceinline__ int lower_bound_i32(const int* __restrict__ a, int n, int v) {
    int lo = 0, hi = n;
    while (lo < hi) {
        int mid = (lo + hi) >> 1;
        if (a[mid] < v) lo = mid + 1; else hi = mid;
    }
    return lo;
}

__global__ void bounds_kernel(const int* __restrict__ batch, int* __restrict__ bounds,
                              int N, int G) {
    int g = blockIdx.x * blockDim.x + threadIdx.x;
    if (g < G)  bounds[g] = lower_bound_i32(batch, N, g);
    if (g == G) bounds[G] = N;
}

__global__ __launch_bounds__(256, 8)
void partial_kernel(const float* __restrict__ x,
                    const int* __restrict__ bounds,
                    float* __restrict__ pmax,          // [G][WSL][DIM]
                    int* __restrict__ pam,             // [G][WSL][DIM]
                    unsigned int* __restrict__ ptie)   // [G][WSL][64] bitmasks
{
    const int bid = blockIdx.x;          // g*4 + s
    const int g = bid >> 2;
    const int s = bid & 3;
    const int w = threadIdx.x >> 6;
    const int l = threadIdx.x & 63;
    const int wi = s * 4 + w;            // wave-slice 0..15

    const int start = bounds[g];
    const int end   = bounds[g + 1];
    const int len   = end - start;
    const int q     = (len + WSL - 1) / WSL;

    int a = start + wi * q;
    int b = a + q;
    if (a > end) a = end;
    if (b > end) b = end;
    const int n = b - a;

    const float NI = -__builtin_huge_valf();
    float m0 = NI, m1 = NI, m2 = NI, m3 = NI;
    int   a0 = -1, a1 = -1, a2 = -1, a3 = -1;
    unsigned int tieb = 0;

    // row r (relative to a), lane l -> p[r*64]
    const f32x4* __restrict__ p = (const f32x4*)x + (size_t)a * 64 + l;

#define LD(r) __builtin_nontemporal_load(p + (size_t)(r) * 64)
#define UPD4(v, idx) do {                                             \
        bool g0 = (v).x > m0, g1 = (v).y > m1,                        \
             g2 = (v).z > m2, g3 = (v).w > m3;                        \
        tieb |= ((v).x == m0) ? 1u : 0u;                              \
        tieb |= ((v).y == m1) ? 2u : 0u;                              \
        tieb |= ((v).z == m2) ? 4u : 0u;                              \
        tieb |= ((v).w == m3) ? 8u : 0u;                              \
        a0 = g0 ? (idx) : a0;  m0 = g0 ? (v).x : m0;                  \
        a1 = g1 ? (idx) : a1;  m1 = g1 ? (v).y : m1;                  \
        a2 = g2 ? (idx) : a2;  m2 = g2 ? (v).z : m2;                  \
        a3 = g3 ? (idx) : a3;  m3 = g3 ? (v).w : m3;                  \
    } while (0)

    // 4-deep prefetch ring, statically indexed
    f32x4 f0 = (f32x4)(NI), f1 = f0, f2 = f0, f3 = f0;
    if (n > 0) f0 = LD(0);
    if (n > 1) f1 = LD(1);
    if (n > 2) f2 = LD(2);
    if (n > 3) f3 = LD(3);

    int k = 0;
    for (; k + 8 <= n; k += 4) {
        UPD4(f0, a + k + 0);  f0 = LD(k + 4);
        UPD4(f1, a + k + 1);  f1 = LD(k + 5);
        UPD4(f2, a + k + 2);  f2 = LD(k + 6);
        UPD4(f3, a + k + 3);  f3 = LD(k + 7);
    }
    const int rem = n - k;   // 0..7
    if (rem > 0) UPD4(f0, a + k + 0);
    if (rem > 1) UPD4(f1, a + k + 1);
    if (rem > 2) UPD4(f2, a + k + 2);
    if (rem > 3) UPD4(f3, a + k + 3);
    for (int r = k + 4; r < n; ++r) {
        f32x4 v = LD(r);
        UPD4(v, a + r);
    }
#undef UPD4
#undef LD

    const size_t base = ((size_t)g * WSL + wi) * DIM + (size_t)l * 4;
    f32x4 mv; mv.x = m0; mv.y = m1; mv.z = m2; mv.w = m3;
    *(f32x4*)(pmax + base) = mv;
    int4 av; av.x = a0; av.y = a1; av.z = a2; av.w = a3;
    *(int4*)(pam + base)   = av;
    ptie[((size_t)g * WSL + wi) * 64 + l] = tieb;   // bits 0..3 = cols 4l..4l+3
}

__global__ __launch_bounds__(256, 8)
void final_kernel(const float* __restrict__ x,
                  const int* __restrict__ bounds,
                  const float* __restrict__ pmax,
                  const int* __restrict__ pam,
                  const unsigned int* __restrict__ ptie,
                  float* __restrict__ emb,
                  float* __restrict__ scores)
{
    const int g = blockIdx.x;
    const int t = threadIdx.x;
    const int start = bounds[g];
    const int end   = bounds[g + 1];

    // zero this graph's scores region
    for (int j = start + t; j < end; j += DIM) scores[j] = 0.0f;

    // combine 16 partials for column t
    const size_t pb = (size_t)g * WSL * DIM + t;
    float pv[WSL];
    #pragma unroll
    for (int i = 0; i < WSL; ++i) pv[i] = pmax[pb + (size_t)i * DIM];

    float M = -__builtin_huge_valf();
    #pragma unroll
    for (int i = 0; i < WSL; ++i) M = fmaxf(M, pv[i]);
    emb[(size_t)g * DIM + t] = fmaxf(M, NEG_CLAMP);

    __syncthreads();   // zeros visible before marking

    bool rescan = false;
    #pragma unroll
    for (int i = 0; i < WSL; ++i) {
        if (pv[i] == M) {
            const int am = pam[pb + (size_t)i * DIM];
            if (am >= 0) scores[am] = 1.0f;      // duplicate 1.0 stores benign
            rescan = rescan ||
                (((ptie[((size_t)g * WSL + i) * 64 + (t >> 2)] >> (t & 3)) & 1u) != 0u);
        }
    }
    if (rescan) {
        // rare: exact duplicate of a slice's running max in a max-attaining
        // slice; re-scan column t, mark every exact hit of the final max.
        const float* __restrict__ col = x + t;
        for (int j = start; j < end; ++j)
            if (col[(size_t)j * DIM] == M) scores[j] = 1.0f;
    }
    __syncthreads();   // all 1-writes visible before counting

    float cnt = 0.0f;
    for (int j = start + t; j < end; j += DIM) cnt += scores[j];
    for (int off = 32; off > 0; off >>= 1) cnt += __shfl_down(cnt, off, 64);

    __shared__ float sred[4];
    const int w = t >> 6, l = t & 63;
    if (l == 0) sred[w] = cnt;
    __syncthreads();
    const float total = sred[0] + sred[1] + sred[2] + sred[3];
    const float inv = 1.0f / fmaxf(total, 1.0f);  // exact: numerator is 0 or 1

    for (int j = start + t; j < end; j += DIM) scores[j] *= inv;
}

extern "C" void kernel_launch(void* const* d_in, const int* in_sizes, int n_in,
                              void* d_out, int out_size, void* d_ws, size_t ws_size,
                              hipStream_t stream) {
    const float* x     = (const float*)d_in[0];
    const int*   batch = (const int*)d_in[1];

    const int N  = in_sizes[1];          // 1048576
    const int Dd = in_sizes[0] / N;      // 256
    const int G  = (out_size - N) / Dd;  // 2048

    float* emb    = (float*)d_out;
    float* scores = (float*)d_out + (size_t)G * Dd;

    // workspace layout (≈75 MB; ws is ~4 GB)
    char* ws = (char*)d_ws;
    int* bounds = (int*)ws;
    size_t off = (((size_t)(G + 1) * sizeof(int)) + 1023) & ~(size_t)1023;
    float* pmax = (float*)(ws + off);  off += (size_t)G * WSL * DIM * sizeof(float);
    int*   pam  = (int*)(ws + off);    off += (size_t)G * WSL * DIM * sizeof(int);
    unsigned int* ptie = (unsigned int*)(ws + off);

    bounds_kernel<<<(G + 256) / 256, 256, 0, stream>>>(batch, bounds, N, G);
    partial_kernel<<<G * 4, 256, 0, stream>>>(x, bounds, pmax, pam, ptie);
    final_kernel<<<G, 256, 0, stream>>>(x, bounds, pmax, pam, ptie, emb, scores);
}